// Round 1
// baseline (82.422 us; speedup 1.0000x reference)
//
#include <hip/hip_runtime.h>

// MeanAggregator: out[n][d] = mean_{s<10} embedding[neigh_idx[n][s]][d]
// N=100000, S=10, V=200000, D=128, f32.
//
// Layout: 32 lanes per node, each lane owns a float4 slice of D=128.
// One embedding row gather = 32 lanes x 16B = 512B coalesced.

#define S_NEIGH 10
#define D_DIM   128

__global__ __launch_bounds__(256) void MeanAggregator_kernel(
    const int* __restrict__ idx,        // [N, S]
    const float* __restrict__ emb,      // [V, D]
    float* __restrict__ out,            // [N, D]
    int N)
{
    const int gid   = blockIdx.x * blockDim.x + threadIdx.x;
    const int node  = gid >> 5;        // 32 threads per node
    const int lane4 = gid & 31;        // which float4 of the 128-wide row
    if (node >= N) return;

    const int* ip = idx + (size_t)node * S_NEIGH;

    float4 acc = make_float4(0.f, 0.f, 0.f, 0.f);
    #pragma unroll
    for (int s = 0; s < S_NEIGH; ++s) {
        const int v = ip[s];   // same address across the 32-lane group: broadcast
        const float4 e = *reinterpret_cast<const float4*>(
            emb + (size_t)v * D_DIM + lane4 * 4);
        acc.x += e.x; acc.y += e.y; acc.z += e.z; acc.w += e.w;
    }

    const float inv = 1.0f / (float)S_NEIGH;
    float4 r = make_float4(acc.x * inv, acc.y * inv, acc.z * inv, acc.w * inv);
    *reinterpret_cast<float4*>(out + (size_t)node * D_DIM + lane4 * 4) = r;
}

extern "C" void kernel_launch(void* const* d_in, const int* in_sizes, int n_in,
                              void* d_out, int out_size, void* d_ws, size_t ws_size,
                              hipStream_t stream) {
    const int*   idx = (const int*)d_in[0];     // neigh_idx [N,S] (int)
    const float* emb = (const float*)d_in[1];   // embedding [V,D] f32
    float*       out = (float*)d_out;           // [N,D] f32

    const int N = in_sizes[0] / S_NEIGH;        // 100000

    const int threads = 256;                    // 8 nodes per block
    const int total   = N * 32;                 // 32 threads per node
    const int blocks  = (total + threads - 1) / threads;

    MeanAggregator_kernel<<<blocks, threads, 0, stream>>>(idx, emb, out, N);
}